// Round 6
// baseline (1692.976 us; speedup 1.0000x reference)
//
#include <hip/hip_runtime.h>

#define NTT 100000
#define NAA 50000
#define NBB 50000
#define NEE 500000
#define DD  128

typedef short s16x4 __attribute__((ext_vector_type(4)));
typedef float f32x4 __attribute__((ext_vector_type(4)));

// ---------------------------------------------------------------------------
// Weight convert: fp32 W[k][col] (128x128) -> bf16 W^T stored [col][k]
// 7 matrices -> out[m*16384 + col*128 + k]
// ---------------------------------------------------------------------------
struct WP { const float* p[7]; };

__global__ __launch_bounds__(256) void wconv_kernel(WP wp, unsigned short* out) {
    int idx = blockIdx.x * 256 + threadIdx.x;
    if (idx >= 7 * 16384) return;
    int m = idx >> 14;
    int r = idx & 16383;
    int col = r >> 7;
    int k = r & 127;
    float v = wp.p[m][k * 128 + col];
    union { __bf16 b; unsigned short u; } cv;
    cv.b = (__bf16)v;
    out[idx] = cv.u;
}

// ---------------------------------------------------------------------------
// Scatter-add segment sum: out[dst[e]] += feat[src[e]]  (rows of 128 f32)
// One wave per edge; lane l handles elements l and l+64 (contiguous 256B).
// ---------------------------------------------------------------------------
__global__ __launch_bounds__(256) void scatter_kernel(const float* __restrict__ feat,
                                                      const int* __restrict__ src,
                                                      const int* __restrict__ dst,
                                                      float* out, int nE) {
    int gtid = blockIdx.x * blockDim.x + threadIdx.x;
    int wid = gtid >> 6;
    int l = gtid & 63;
    int nw = (gridDim.x * blockDim.x) >> 6;
    for (int e = wid; e < nE; e += nw) {
        int s = src[e];
        int d = dst[e];
        const float* pi = feat + (size_t)s * DD;
        float* po = out + (size_t)d * DD;
        float v0 = pi[l];
        float v1 = pi[l + 64];
        unsafeAtomicAdd(po + l, v0);
        unsafeAtomicAdd(po + l + 64, v1);
    }
}

// ---------------------------------------------------------------------------
// Fused GEMM kernel: out = f(X) @ W + bias, with mode-specific pre/epilogue.
// MODE 0: x = (1+eps)*X + AADD ; z = acc+b ; store z ; accumulate stats
// MODE 1: x = X               ; z = acc+b ; store z ; accumulate stats
// MODE 2: x = relu(X*sc+sh)   ; o = acc+b ; store o
// MODE 3: x = X               ; u = (1+eps)*(acc+b) + out[r][c] ; store u (in-place)
// Block: 256 threads / 4 waves; 64 rows x 128 cols per block.
// W^T bf16 staged in LDS with XOR swizzle (byte ^= (col&7)<<4).
// MFMA: legacy 16x16x16 bf16 (classic layout).
// ---------------------------------------------------------------------------
template <int MODE>
__global__ __launch_bounds__(256) void mlp_kernel(const float* X,
                                                  const float* __restrict__ AADD,
                                                  const float* __restrict__ eps_ptr,
                                                  const float* __restrict__ ss,
                                                  const unsigned short* __restrict__ Wt,
                                                  const float* __restrict__ bias,
                                                  float* out, float* stats, int N) {
    __shared__ __align__(16) unsigned char lds[128 * 128 * 2];
    const int tid = threadIdx.x;

    // stage W^T (32KB bf16) into LDS, swizzled
#pragma unroll
    for (int i = 0; i < 8; ++i) {
        int c = tid + i * 256;          // 16B chunk id, 0..2047
        int col = c >> 4;               // 16 chunks per column
        uint4 wv = ((const uint4*)Wt)[c];
        int off = (c * 16) ^ ((col & 7) << 4);
        *(uint4*)(lds + off) = wv;
    }

    const int w = tid >> 6;
    const int l = tid & 63;
    const int rl = l & 15;
    const int grp = l >> 4;
    const int row_base = blockIdx.x * 64 + w * 16;
    const int arow = row_base + rl;
    const bool aok = arow < N;

    float eps1 = 0.f;
    if (MODE == 0 || MODE == 3) eps1 = 1.f + eps_ptr[0];

    // A fragments: 8 K-chunks of 4 bf16 (k = kc*16 + grp*4 + j)
    s16x4 af[8];
#pragma unroll
    for (int kc = 0; kc < 8; ++kc) {
        int k0 = kc * 16 + grp * 4;
        float4 v = make_float4(0.f, 0.f, 0.f, 0.f);
        if (aok) {
            v = *(const float4*)(X + (size_t)arow * DD + k0);
            if (MODE == 0) {
                float4 a = *(const float4*)(AADD + (size_t)arow * DD + k0);
                v.x = eps1 * v.x + a.x;
                v.y = eps1 * v.y + a.y;
                v.z = eps1 * v.z + a.z;
                v.w = eps1 * v.w + a.w;
            } else if (MODE == 2) {
                float4 sc = *(const float4*)(ss + k0);
                float4 sh = *(const float4*)(ss + 128 + k0);
                v.x = fmaxf(v.x * sc.x + sh.x, 0.f);
                v.y = fmaxf(v.y * sc.y + sh.y, 0.f);
                v.z = fmaxf(v.z * sc.z + sh.z, 0.f);
                v.w = fmaxf(v.w * sc.w + sh.w, 0.f);
            }
        }
        union { __bf16 b[4]; s16x4 s; } u;
        u.b[0] = (__bf16)v.x;
        u.b[1] = (__bf16)v.y;
        u.b[2] = (__bf16)v.z;
        u.b[3] = (__bf16)v.w;
        af[kc] = u.s;
    }
    __syncthreads();

    // 8 column tiles of 16
#pragma unroll
    for (int ct = 0; ct < 8; ++ct) {
        const int col = ct * 16 + rl;
        f32x4 acc = {0.f, 0.f, 0.f, 0.f};
#pragma unroll
        for (int kc = 0; kc < 8; ++kc) {
            int kb = (kc * 16 + grp * 4) * 2;   // byte offset within column
            int off = (col * 256 + kb) ^ ((col & 7) << 4);
            s16x4 bf = *(const s16x4*)(lds + off);
            acc = __builtin_amdgcn_mfma_f32_16x16x16bf16_1k(af[kc], bf, acc, 0, 0, 0);
        }
        float b = bias[col];
        float lsum = 0.f, lsq = 0.f;
#pragma unroll
        for (int r = 0; r < 4; ++r) {
            int row = row_base + grp * 4 + r;
            if (row < N) {
                float zv = acc[r] + b;
                if (MODE == 3) {
                    float* po = out + (size_t)row * DD + col;
                    zv = eps1 * zv + *po;
                    *po = zv;
                } else {
                    out[(size_t)row * DD + col] = zv;
                }
                if (MODE == 0 || MODE == 1) {
                    lsum += zv;
                    lsq += zv * zv;
                }
            }
        }
        if (MODE == 0 || MODE == 1) {
            lsum += __shfl_xor(lsum, 16);
            lsq  += __shfl_xor(lsq, 16);
            lsum += __shfl_xor(lsum, 32);
            lsq  += __shfl_xor(lsq, 32);
            if (grp == 0) {
                unsafeAtomicAdd(&stats[col], lsum);
                unsafeAtomicAdd(&stats[128 + col], lsq);
            }
        }
    }
}

// ---------------------------------------------------------------------------
// BN finalize: per-column scale/shift from accumulated sum/sumsq.
// ---------------------------------------------------------------------------
__global__ void bnfin_kernel(const float* __restrict__ stats,
                             const float* __restrict__ g,
                             const float* __restrict__ beta,
                             float invN, float* ss) {
    int c = threadIdx.x;
    float mu = stats[c] * invN;
    float var = stats[128 + c] * invN - mu * mu;
    float sc = g[c] * rsqrtf(var + 1e-5f);
    ss[c] = sc;
    ss[128 + c] = beta[c] - mu * sc;
}

// ---------------------------------------------------------------------------

static inline int mlp_grid(int n) { return (n + 63) / 64; }

extern "C" void kernel_launch(void* const* d_in, const int* in_sizes, int n_in,
                              void* d_out, int out_size, void* d_ws, size_t ws_size,
                              hipStream_t stream) {
    const float* hT = (const float*)d_in[0];
    const float* hA = (const float*)d_in[1];
    const float* hB = (const float*)d_in[2];
    const int* src_ta = (const int*)d_in[3];
    const int* dst_ta = (const int*)d_in[4];
    const int* src_tb = (const int*)d_in[5];
    const int* dst_tb = (const int*)d_in[6];
    const int* src_at = (const int*)d_in[7];
    const int* dst_at = (const int*)d_in[8];
    const int* src_bt = (const int*)d_in[9];
    const int* dst_bt = (const int*)d_in[10];
    const float* eps_ta = (const float*)d_in[11];
    const float* eps_tb = (const float*)d_in[12];
    const float* eps_ret = (const float*)d_in[13];
    const float* ta_b1 = (const float*)d_in[15];
    const float* ta_g = (const float*)d_in[16];
    const float* ta_beta = (const float*)d_in[17];
    const float* ta_b2 = (const float*)d_in[19];
    const float* tb_b1 = (const float*)d_in[21];
    const float* tb_g = (const float*)d_in[22];
    const float* tb_beta = (const float*)d_in[23];
    const float* tb_b2 = (const float*)d_in[25];
    const float* ret_b1 = (const float*)d_in[27];
    const float* ret_g = (const float*)d_in[28];
    const float* ret_beta = (const float*)d_in[29];
    const float* ret_b2 = (const float*)d_in[31];
    const float* bp = (const float*)d_in[33];

    float* out = (float*)d_out;
    float* z  = out;                             // [NTT*128] scratch; final hT_new
    float* aA = out + (size_t)NTT * DD;          // [NAA*128]; becomes hA_new
    float* aB = aA + (size_t)NAA * DD;           // [NBB*128]; becomes hB_new

    char* ws = (char*)d_ws;
    float* aT = (float*)ws;                      // [NTT*128]; becomes u (in-place)
    unsigned short* Wt = (unsigned short*)(ws + (size_t)NTT * DD * 4);
    float* stats = (float*)(ws + (size_t)NTT * DD * 4 + (size_t)7 * 16384 * 2);
    float* ssb = stats + 768;                    // scale/shift: 3 x 256

    // zero aggregation buffers + stats
    hipMemsetAsync(aA, 0, (size_t)(NAA + NBB) * DD * 4, stream);
    hipMemsetAsync(aT, 0, (size_t)NTT * DD * 4, stream);
    hipMemsetAsync(stats, 0, 768 * 4, stream);

    // convert weights to bf16 W^T
    WP wp;
    wp.p[0] = (const float*)d_in[14];  // ta_W1
    wp.p[1] = (const float*)d_in[18];  // ta_W2
    wp.p[2] = (const float*)d_in[20];  // tb_W1
    wp.p[3] = (const float*)d_in[24];  // tb_W2
    wp.p[4] = (const float*)d_in[26];  // ret_W1
    wp.p[5] = (const float*)d_in[30];  // ret_W2
    wp.p[6] = (const float*)d_in[32];  // Wp
    wconv_kernel<<<(7 * 16384 + 255) / 256, 256, 0, stream>>>(wp, Wt);

    // go-path segment sums
    scatter_kernel<<<1024, 256, 0, stream>>>(hT, src_ta, dst_ta, aA, NEE);
    scatter_kernel<<<1024, 256, 0, stream>>>(hT, src_tb, dst_tb, aB, NEE);

    // ta MLP
    mlp_kernel<0><<<mlp_grid(NAA), 256, 0, stream>>>(hA, aA, eps_ta, nullptr,
                                                     Wt + 0 * 16384, ta_b1, z, stats + 0, NAA);
    bnfin_kernel<<<1, 128, 0, stream>>>(stats + 0, ta_g, ta_beta, 1.f / NAA, ssb + 0);
    mlp_kernel<2><<<mlp_grid(NAA), 256, 0, stream>>>(z, nullptr, nullptr, ssb + 0,
                                                     Wt + 1 * 16384, ta_b2, aA, nullptr, NAA);

    // tb MLP
    mlp_kernel<0><<<mlp_grid(NBB), 256, 0, stream>>>(hB, aB, eps_tb, nullptr,
                                                     Wt + 2 * 16384, tb_b1, z, stats + 256, NBB);
    bnfin_kernel<<<1, 128, 0, stream>>>(stats + 256, tb_g, tb_beta, 1.f / NBB, ssb + 256);
    mlp_kernel<2><<<mlp_grid(NBB), 256, 0, stream>>>(z, nullptr, nullptr, ssb + 256,
                                                     Wt + 3 * 16384, tb_b2, aB, nullptr, NBB);

    // return-path segment sums (hA_new, hB_new live in d_out now)
    scatter_kernel<<<1024, 256, 0, stream>>>(aA, src_at, dst_at, aT, NEE);
    scatter_kernel<<<1024, 256, 0, stream>>>(aB, src_bt, dst_bt, aT, NEE);

    // projection: u = (1+eps_ret)*(hT@Wp + bp) + aT   (in-place into aT)
    mlp_kernel<3><<<mlp_grid(NTT), 256, 0, stream>>>(hT, nullptr, eps_ret, nullptr,
                                                     Wt + 6 * 16384, bp, aT, nullptr, NTT);

    // ret MLP
    mlp_kernel<1><<<mlp_grid(NTT), 256, 0, stream>>>(aT, nullptr, nullptr, nullptr,
                                                     Wt + 4 * 16384, ret_b1, z, stats + 512, NTT);
    bnfin_kernel<<<1, 128, 0, stream>>>(stats + 512, ret_g, ret_beta, 1.f / NTT, ssb + 512);
    mlp_kernel<2><<<mlp_grid(NTT), 256, 0, stream>>>(z, nullptr, nullptr, ssb + 512,
                                                     Wt + 5 * 16384, ret_b2, z, nullptr, NTT);
}

// Round 8
// 1296.417 us; speedup vs baseline: 1.3059x; 1.3059x over previous
//
#include <hip/hip_runtime.h>

#define NTT 100000
#define NAA 50000
#define NBB 50000
#define NEE 500000
#define DD  128
#define NPART 64
#define MLP_GRID 2048

typedef short s16x8 __attribute__((ext_vector_type(8)));
typedef float f32x4 __attribute__((ext_vector_type(4)));

// ---------------------------------------------------------------------------
// Weight convert: fp32 W[k][col] (128x128) -> bf16 W^T stored [col][k]
// 7 matrices -> out[m*16384 + col*128 + k]
// ---------------------------------------------------------------------------
struct WP { const float* p[7]; };

__global__ __launch_bounds__(256) void wconv_kernel(WP wp, unsigned short* out) {
    int idx = blockIdx.x * 256 + threadIdx.x;
    if (idx >= 7 * 16384) return;
    int m = idx >> 14;
    int r = idx & 16383;
    int col = r >> 7;
    int k = r & 127;
    float v = wp.p[m][k * 128 + col];
    union { __bf16 b; unsigned short u; } cv;
    cv.b = (__bf16)v;
    out[idx] = cv.u;
}

// ---------------------------------------------------------------------------
// Scatter-add segment sum: out[dst[e]] += feat[src[e]]  (rows of 128 f32)
// One wave per edge; lane l handles elements l and l+64 (contiguous 256B).
// ---------------------------------------------------------------------------
__global__ __launch_bounds__(256) void scatter_kernel(const float* __restrict__ feat,
                                                      const int* __restrict__ src,
                                                      const int* __restrict__ dst,
                                                      float* out, int nE) {
    int gtid = blockIdx.x * blockDim.x + threadIdx.x;
    int wid = gtid >> 6;
    int l = gtid & 63;
    int nw = (gridDim.x * blockDim.x) >> 6;
    for (int e = wid; e < nE; e += nw) {
        int s = src[e];
        int d = dst[e];
        const float* pi = feat + (size_t)s * DD;
        float* po = out + (size_t)d * DD;
        float v0 = pi[l];
        float v1 = pi[l + 64];
        unsafeAtomicAdd(po + l, v0);
        unsafeAtomicAdd(po + l + 64, v1);
    }
}

// ---------------------------------------------------------------------------
// Reg-B MLP GEMM: out = f(X) @ W + bias.
// 4 waves/block; wave w owns output cols [w*32,w*32+32).
// B (W^T) held in 32 VGPRs/lane, loaded once. Grid-stride over 16-row tiles.
// MFMA: native gfx950 16x16x32 bf16.
//   A: lane(rl,grp): row=rl, k=grp*8+j (+kc*32)   [8 bf16 = s16x8]
//   C/D: col=rl, row=grp*4+reg
// MODE 0: x=(1+eps)*X+AADD ; z=acc+b ; store ; stats
// MODE 1: x=X              ; z=acc+b ; store ; stats
// MODE 2: x=relu(X*sc+sh)  ; store acc+b
//   MODE 2 may run IN-PLACE (X == out, ret path): all waves read the full
//   128 cols of a tile's rows but write only their own 32 cols, so a
//   __syncthreads() between the read phase and the write phase is REQUIRED
//   (round-7 race: removing it gave absmax 2.7 on hT_new). Tiles' row sets
//   are disjoint, so one barrier per iteration suffices.
// MODE 3: x=X              ; store (1+eps)*(acc+b)+out[r][c]  (per-thread RMW)
// Stats: register accumulation, shuffle-reduce, one atomic per (block,col)
// into 64-way partial buffers.
// ---------------------------------------------------------------------------
template <int MODE>
__global__ __launch_bounds__(256) void mlp_kernel(const float* __restrict__ X,
                                                  const float* __restrict__ AADD,
                                                  const float* __restrict__ eps_ptr,
                                                  const float* __restrict__ ss,
                                                  const unsigned short* __restrict__ Wt,
                                                  const float* __restrict__ bias,
                                                  float* __restrict__ out,
                                                  float* __restrict__ statsp,
                                                  int ntiles) {
    const int tid = threadIdx.x;
    const int w = tid >> 6;          // wave 0..3
    const int l = tid & 63;
    const int rl = l & 15;
    const int grp = l >> 4;
    const int wcol = w * 32;

    // B fragments in registers: bq[ct][kc], col = wcol+ct*16+rl, k = kc*32+grp*8+j
    s16x8 bq[2][4];
#pragma unroll
    for (int ct = 0; ct < 2; ++ct)
#pragma unroll
        for (int kc = 0; kc < 4; ++kc)
            bq[ct][kc] = *(const s16x8*)(Wt + (size_t)(wcol + ct * 16 + rl) * DD + kc * 32 + grp * 8);

    const float eps1 = (MODE == 0 || MODE == 3) ? (1.f + eps_ptr[0]) : 0.f;
    float bias_c[2];
#pragma unroll
    for (int ct = 0; ct < 2; ++ct) bias_c[ct] = bias[wcol + ct * 16 + rl];

    float st_s[2] = {0.f, 0.f}, st_q[2] = {0.f, 0.f};

    for (int t = blockIdx.x; t < ntiles; t += gridDim.x) {
        const size_t xbase = (size_t)(t * 16 + rl) * DD;
        s16x8 af[4];
#pragma unroll
        for (int kc = 0; kc < 4; ++kc) {
            const int k0 = kc * 32 + grp * 8;
            float4 v0 = *(const float4*)(X + xbase + k0);
            float4 v1 = *(const float4*)(X + xbase + k0 + 4);
            if (MODE == 0) {
                float4 a0 = *(const float4*)(AADD + xbase + k0);
                float4 a1 = *(const float4*)(AADD + xbase + k0 + 4);
                v0.x = eps1 * v0.x + a0.x; v0.y = eps1 * v0.y + a0.y;
                v0.z = eps1 * v0.z + a0.z; v0.w = eps1 * v0.w + a0.w;
                v1.x = eps1 * v1.x + a1.x; v1.y = eps1 * v1.y + a1.y;
                v1.z = eps1 * v1.z + a1.z; v1.w = eps1 * v1.w + a1.w;
            } else if (MODE == 2) {
                float4 c0 = *(const float4*)(ss + k0);
                float4 c1 = *(const float4*)(ss + k0 + 4);
                float4 s0 = *(const float4*)(ss + 128 + k0);
                float4 s1 = *(const float4*)(ss + 128 + k0 + 4);
                v0.x = fmaxf(v0.x * c0.x + s0.x, 0.f); v0.y = fmaxf(v0.y * c0.y + s0.y, 0.f);
                v0.z = fmaxf(v0.z * c0.z + s0.z, 0.f); v0.w = fmaxf(v0.w * c0.w + s0.w, 0.f);
                v1.x = fmaxf(v1.x * c1.x + s1.x, 0.f); v1.y = fmaxf(v1.y * c1.y + s1.y, 0.f);
                v1.z = fmaxf(v1.z * c1.z + s1.z, 0.f); v1.w = fmaxf(v1.w * c1.w + s1.w, 0.f);
            }
            union { __bf16 h[8]; s16x8 v; } u;
            u.h[0] = (__bf16)v0.x; u.h[1] = (__bf16)v0.y;
            u.h[2] = (__bf16)v0.z; u.h[3] = (__bf16)v0.w;
            u.h[4] = (__bf16)v1.x; u.h[5] = (__bf16)v1.y;
            u.h[6] = (__bf16)v1.z; u.h[7] = (__bf16)v1.w;
            af[kc] = u.v;
        }

        // In-place safety for MODE 2 (X may alias out): all waves' reads of
        // this tile's rows must complete before any wave writes them.
        if (MODE == 2) __syncthreads();

        f32x4 acc[2] = {{0.f, 0.f, 0.f, 0.f}, {0.f, 0.f, 0.f, 0.f}};
#pragma unroll
        for (int kc = 0; kc < 4; ++kc) {
            acc[0] = __builtin_amdgcn_mfma_f32_16x16x32_bf16(af[kc], bq[0][kc], acc[0], 0, 0, 0);
            acc[1] = __builtin_amdgcn_mfma_f32_16x16x32_bf16(af[kc], bq[1][kc], acc[1], 0, 0, 0);
        }

#pragma unroll
        for (int ct = 0; ct < 2; ++ct) {
            const int col = wcol + ct * 16 + rl;
#pragma unroll
            for (int r = 0; r < 4; ++r) {
                const int row = t * 16 + grp * 4 + r;
                float zv = acc[ct][r] + bias_c[ct];
                float* po = out + (size_t)row * DD + col;
                if (MODE == 3) zv = eps1 * zv + *po;
                *po = zv;
                if (MODE == 0 || MODE == 1) {
                    st_s[ct] += zv;
                    st_q[ct] += zv * zv;
                }
            }
        }
    }

    if (MODE == 0 || MODE == 1) {
        const int part = blockIdx.x & (NPART - 1);
#pragma unroll
        for (int ct = 0; ct < 2; ++ct) {
            st_s[ct] += __shfl_xor(st_s[ct], 16);
            st_s[ct] += __shfl_xor(st_s[ct], 32);
            st_q[ct] += __shfl_xor(st_q[ct], 16);
            st_q[ct] += __shfl_xor(st_q[ct], 32);
            if (grp == 0) {
                const int col = wcol + ct * 16 + rl;
                unsafeAtomicAdd(&statsp[part * 256 + col], st_s[ct]);
                unsafeAtomicAdd(&statsp[part * 256 + 128 + col], st_q[ct]);
            }
        }
    }
}

// ---------------------------------------------------------------------------
// BN finalize: reduce 64 partials -> per-column scale/shift.
// ---------------------------------------------------------------------------
__global__ void bnfin_kernel(const float* __restrict__ statsp,
                             const float* __restrict__ g,
                             const float* __restrict__ beta,
                             float invN, float* ss) {
    int c = threadIdx.x;
    float s = 0.f, q = 0.f;
    for (int p = 0; p < NPART; ++p) {
        s += statsp[p * 256 + c];
        q += statsp[p * 256 + 128 + c];
    }
    float mu = s * invN;
    float var = q * invN - mu * mu;
    float sc = g[c] * rsqrtf(var + 1e-5f);
    ss[c] = sc;
    ss[128 + c] = beta[c] - mu * sc;
}

// ---------------------------------------------------------------------------

extern "C" void kernel_launch(void* const* d_in, const int* in_sizes, int n_in,
                              void* d_out, int out_size, void* d_ws, size_t ws_size,
                              hipStream_t stream) {
    const float* hT = (const float*)d_in[0];
    const float* hA = (const float*)d_in[1];
    const float* hB = (const float*)d_in[2];
    const int* src_ta = (const int*)d_in[3];
    const int* dst_ta = (const int*)d_in[4];
    const int* src_tb = (const int*)d_in[5];
    const int* dst_tb = (const int*)d_in[6];
    const int* src_at = (const int*)d_in[7];
    const int* dst_at = (const int*)d_in[8];
    const int* src_bt = (const int*)d_in[9];
    const int* dst_bt = (const int*)d_in[10];
    const float* eps_ta = (const float*)d_in[11];
    const float* eps_tb = (const float*)d_in[12];
    const float* eps_ret = (const float*)d_in[13];
    const float* ta_b1 = (const float*)d_in[15];
    const float* ta_g = (const float*)d_in[16];
    const float* ta_beta = (const float*)d_in[17];
    const float* ta_b2 = (const float*)d_in[19];
    const float* tb_b1 = (const float*)d_in[21];
    const float* tb_g = (const float*)d_in[22];
    const float* tb_beta = (const float*)d_in[23];
    const float* tb_b2 = (const float*)d_in[25];
    const float* ret_b1 = (const float*)d_in[27];
    const float* ret_g = (const float*)d_in[28];
    const float* ret_beta = (const float*)d_in[29];
    const float* ret_b2 = (const float*)d_in[31];
    const float* bp = (const float*)d_in[33];

    float* out = (float*)d_out;
    float* z  = out;                             // [NTT*128] scratch; final hT_new
    float* aA = out + (size_t)NTT * DD;          // [NAA*128]; becomes hA_new
    float* aB = aA + (size_t)NAA * DD;           // [NBB*128]; becomes hB_new

    char* ws = (char*)d_ws;
    float* aT = (float*)ws;                      // [NTT*128]; becomes u (in-place)
    unsigned short* Wt = (unsigned short*)(ws + (size_t)NTT * DD * 4);
    float* statsp = (float*)(ws + (size_t)NTT * DD * 4 + (size_t)7 * 16384 * 2);
    float* ssb = statsp + 3 * NPART * 256;       // scale/shift: 3 x 256

    // zero aggregation buffers + stats partials
    hipMemsetAsync(aA, 0, (size_t)(NAA + NBB) * DD * 4, stream);
    hipMemsetAsync(aT, 0, (size_t)NTT * DD * 4, stream);
    hipMemsetAsync(statsp, 0, (size_t)3 * NPART * 256 * 4, stream);

    // convert weights to bf16 W^T
    WP wp;
    wp.p[0] = (const float*)d_in[14];  // ta_W1
    wp.p[1] = (const float*)d_in[18];  // ta_W2
    wp.p[2] = (const float*)d_in[20];  // tb_W1
    wp.p[3] = (const float*)d_in[24];  // tb_W2
    wp.p[4] = (const float*)d_in[26];  // ret_W1
    wp.p[5] = (const float*)d_in[30];  // ret_W2
    wp.p[6] = (const float*)d_in[32];  // Wp
    wconv_kernel<<<(7 * 16384 + 255) / 256, 256, 0, stream>>>(wp, Wt);

    // go-path segment sums
    scatter_kernel<<<1024, 256, 0, stream>>>(hT, src_ta, dst_ta, aA, NEE);
    scatter_kernel<<<1024, 256, 0, stream>>>(hT, src_tb, dst_tb, aB, NEE);

    // ta MLP
    mlp_kernel<0><<<MLP_GRID, 256, 0, stream>>>(hA, aA, eps_ta, nullptr,
                                                Wt + 0 * 16384, ta_b1, z,
                                                statsp + 0 * NPART * 256, NAA / 16);
    bnfin_kernel<<<1, 128, 0, stream>>>(statsp + 0 * NPART * 256, ta_g, ta_beta,
                                        1.f / NAA, ssb + 0);
    mlp_kernel<2><<<MLP_GRID, 256, 0, stream>>>(z, nullptr, nullptr, ssb + 0,
                                                Wt + 1 * 16384, ta_b2, aA,
                                                nullptr, NAA / 16);

    // tb MLP
    mlp_kernel<0><<<MLP_GRID, 256, 0, stream>>>(hB, aB, eps_tb, nullptr,
                                                Wt + 2 * 16384, tb_b1, z,
                                                statsp + 1 * NPART * 256, NBB / 16);
    bnfin_kernel<<<1, 128, 0, stream>>>(statsp + 1 * NPART * 256, tb_g, tb_beta,
                                        1.f / NBB, ssb + 256);
    mlp_kernel<2><<<MLP_GRID, 256, 0, stream>>>(z, nullptr, nullptr, ssb + 256,
                                                Wt + 3 * 16384, tb_b2, aB,
                                                nullptr, NBB / 16);

    // return-path segment sums (hA_new, hB_new live in d_out now)
    scatter_kernel<<<1024, 256, 0, stream>>>(aA, src_at, dst_at, aT, NEE);
    scatter_kernel<<<1024, 256, 0, stream>>>(aB, src_bt, dst_bt, aT, NEE);

    // projection: u = (1+eps_ret)*(hT@Wp + bp) + aT   (in-place into aT)
    mlp_kernel<3><<<MLP_GRID, 256, 0, stream>>>(hT, nullptr, eps_ret, nullptr,
                                                Wt + 6 * 16384, bp, aT,
                                                nullptr, NTT / 16);

    // ret MLP
    mlp_kernel<1><<<MLP_GRID, 256, 0, stream>>>(aT, nullptr, nullptr, nullptr,
                                                Wt + 4 * 16384, ret_b1, z,
                                                statsp + 2 * NPART * 256, NTT / 16);
    bnfin_kernel<<<1, 128, 0, stream>>>(statsp + 2 * NPART * 256, ret_g, ret_beta,
                                        1.f / NTT, ssb + 512);
    mlp_kernel<2><<<MLP_GRID, 256, 0, stream>>>(z, nullptr, nullptr, ssb + 512,
                                                Wt + 5 * 16384, ret_b2, z,
                                                nullptr, NTT / 16);
}

// Round 10
// 863.993 us; speedup vs baseline: 1.9595x; 1.5005x over previous
//
#include <hip/hip_runtime.h>

#define NTT 100000
#define NAA 50000
#define NBB 50000
#define NEE 500000
#define DD  128
#define NPART 64
#define MLP_GRID 2048

typedef short s16x8 __attribute__((ext_vector_type(8)));
typedef float f32x4 __attribute__((ext_vector_type(4)));
typedef unsigned short ushort_t;

__device__ inline float bf2f(unsigned short u) {
    union { unsigned int i; float f; } c;
    c.i = ((unsigned int)u) << 16;
    return c.f;
}

// ---------------------------------------------------------------------------
// Weight convert: fp32 W[k][col] (128x128) -> bf16 W^T stored [col][k]
// ---------------------------------------------------------------------------
struct WP { const float* p[7]; };

__global__ __launch_bounds__(256) void wconv_kernel(WP wp, ushort_t* out) {
    int idx = blockIdx.x * 256 + threadIdx.x;
    if (idx >= 7 * 16384) return;
    int m = idx >> 14;
    int r = idx & 16383;
    int col = r >> 7;
    int k = r & 127;
    float v = wp.p[m][k * 128 + col];
    union { __bf16 b; unsigned short u; } cv;
    cv.b = (__bf16)v;
    out[idx] = cv.u;
}

// ---------------------------------------------------------------------------
// Scatter-add segment sum into BF16 rows via packed bf16 atomics.
// agg[dst[e]] += feat[src[e]] ; one wave per edge; lane l owns cols 2l,2l+1.
// Round-8 PMC showed f32 scatter is memory-side RMW-count-bound (8 line-RMWs
// per edge, 19G lines/s ceiling); pk_add_bf16 halves that to 4.
// ---------------------------------------------------------------------------
__global__ __launch_bounds__(256) void scatter_pk_kernel(const float* __restrict__ feat,
                                                         const int* __restrict__ src,
                                                         const int* __restrict__ dst,
                                                         ushort_t* agg, int nE) {
    int gtid = blockIdx.x * blockDim.x + threadIdx.x;
    int wid = gtid >> 6;
    int l = gtid & 63;
    int nw = (gridDim.x * blockDim.x) >> 6;
    for (int e = wid; e < nE; e += nw) {
        int s = src[e];
        int d = dst[e];
        const float2 v = *(const float2*)(feat + (size_t)s * DD + 2 * l);
        union { __bf16 b[2]; unsigned int u; } p;
        p.b[0] = (__bf16)v.x;
        p.b[1] = (__bf16)v.y;
        ushort_t* pa = agg + (size_t)d * DD + 2 * l;
        asm volatile("global_atomic_pk_add_bf16 %0, %1, off"
                     :: "v"(pa), "v"(p.u) : "memory");
    }
}

// ---------------------------------------------------------------------------
// Reg-B MLP GEMM: out = f(X) @ W + bias. 4 waves/block, wave owns 32 cols.
// MFMA 16x16x32 bf16; A: row=rl,k=grp*8+j; C/D: col=rl,row=grp*4+reg.
// MODE 0: X f32, AADD bf16 ; x=(1+eps)*X+A ; store z f32 ; stats
// MODE 1: X bf16 (u)       ; x=X           ; store z f32 ; stats
// MODE 2: X f32            ; x=relu(X*sc+sh); store f32
//         (may run in-place X==out -> barrier between read and write phases;
//          round-7 race without it: absmax 2.7)
// MODE 3: X f32 (hT), out bf16 (aggT): *po = bf16(eps1*(acc+b) + f32(*po))
//         per-thread-exclusive RMW.
// ---------------------------------------------------------------------------
template <int MODE>
__global__ __launch_bounds__(256) void mlp_kernel(const void* __restrict__ Xv,
                                                  const void* __restrict__ Av,
                                                  const float* __restrict__ eps_ptr,
                                                  const float* __restrict__ ss,
                                                  const ushort_t* __restrict__ Wt,
                                                  const float* __restrict__ bias,
                                                  void* __restrict__ outv,
                                                  float* __restrict__ statsp,
                                                  int ntiles) {
    const float* X = (const float*)Xv;
    const ushort_t* Xb = (const ushort_t*)Xv;
    const ushort_t* A = (const ushort_t*)Av;
    float* out = (float*)outv;
    ushort_t* outb = (ushort_t*)outv;

    const int tid = threadIdx.x;
    const int w = tid >> 6;
    const int l = tid & 63;
    const int rl = l & 15;
    const int grp = l >> 4;
    const int wcol = w * 32;

    s16x8 bq[2][4];
#pragma unroll
    for (int ct = 0; ct < 2; ++ct)
#pragma unroll
        for (int kc = 0; kc < 4; ++kc)
            bq[ct][kc] = *(const s16x8*)(Wt + (size_t)(wcol + ct * 16 + rl) * DD + kc * 32 + grp * 8);

    const float eps1 = (MODE == 0 || MODE == 3) ? (1.f + eps_ptr[0]) : 0.f;
    float bias_c[2];
#pragma unroll
    for (int ct = 0; ct < 2; ++ct) bias_c[ct] = bias[wcol + ct * 16 + rl];

    float st_s[2] = {0.f, 0.f}, st_q[2] = {0.f, 0.f};

    for (int t = blockIdx.x; t < ntiles; t += gridDim.x) {
        const size_t xbase = (size_t)(t * 16 + rl) * DD;
        s16x8 af[4];
#pragma unroll
        for (int kc = 0; kc < 4; ++kc) {
            const int k0 = kc * 32 + grp * 8;
            if (MODE == 1) {
                af[kc] = *(const s16x8*)(Xb + xbase + k0);
            } else {
                float4 v0 = *(const float4*)(X + xbase + k0);
                float4 v1 = *(const float4*)(X + xbase + k0 + 4);
                if (MODE == 0) {
                    s16x8 av = *(const s16x8*)(A + xbase + k0);
                    v0.x = eps1 * v0.x + bf2f((unsigned short)av[0]);
                    v0.y = eps1 * v0.y + bf2f((unsigned short)av[1]);
                    v0.z = eps1 * v0.z + bf2f((unsigned short)av[2]);
                    v0.w = eps1 * v0.w + bf2f((unsigned short)av[3]);
                    v1.x = eps1 * v1.x + bf2f((unsigned short)av[4]);
                    v1.y = eps1 * v1.y + bf2f((unsigned short)av[5]);
                    v1.z = eps1 * v1.z + bf2f((unsigned short)av[6]);
                    v1.w = eps1 * v1.w + bf2f((unsigned short)av[7]);
                } else if (MODE == 2) {
                    float4 c0 = *(const float4*)(ss + k0);
                    float4 c1 = *(const float4*)(ss + k0 + 4);
                    float4 s0 = *(const float4*)(ss + 128 + k0);
                    float4 s1 = *(const float4*)(ss + 128 + k0 + 4);
                    v0.x = fmaxf(v0.x * c0.x + s0.x, 0.f); v0.y = fmaxf(v0.y * c0.y + s0.y, 0.f);
                    v0.z = fmaxf(v0.z * c0.z + s0.z, 0.f); v0.w = fmaxf(v0.w * c0.w + s0.w, 0.f);
                    v1.x = fmaxf(v1.x * c1.x + s1.x, 0.f); v1.y = fmaxf(v1.y * c1.y + s1.y, 0.f);
                    v1.z = fmaxf(v1.z * c1.z + s1.z, 0.f); v1.w = fmaxf(v1.w * c1.w + s1.w, 0.f);
                }
                union { __bf16 h[8]; s16x8 v; } u;
                u.h[0] = (__bf16)v0.x; u.h[1] = (__bf16)v0.y;
                u.h[2] = (__bf16)v0.z; u.h[3] = (__bf16)v0.w;
                u.h[4] = (__bf16)v1.x; u.h[5] = (__bf16)v1.y;
                u.h[6] = (__bf16)v1.z; u.h[7] = (__bf16)v1.w;
                af[kc] = u.v;
            }
        }

        if (MODE == 2) __syncthreads();   // in-place safety (X may alias out)

        f32x4 acc[2] = {{0.f, 0.f, 0.f, 0.f}, {0.f, 0.f, 0.f, 0.f}};
#pragma unroll
        for (int kc = 0; kc < 4; ++kc) {
            acc[0] = __builtin_amdgcn_mfma_f32_16x16x32_bf16(af[kc], bq[0][kc], acc[0], 0, 0, 0);
            acc[1] = __builtin_amdgcn_mfma_f32_16x16x32_bf16(af[kc], bq[1][kc], acc[1], 0, 0, 0);
        }

#pragma unroll
        for (int ct = 0; ct < 2; ++ct) {
            const int col = wcol + ct * 16 + rl;
#pragma unroll
            for (int r = 0; r < 4; ++r) {
                const int row = t * 16 + grp * 4 + r;
                float zv = acc[ct][r] + bias_c[ct];
                if (MODE == 3) {
                    ushort_t* po = outb + (size_t)row * DD + col;
                    zv = eps1 * zv + bf2f(*po);
                    union { __bf16 b; unsigned short u; } cv;
                    cv.b = (__bf16)zv;
                    *po = cv.u;
                } else {
                    out[(size_t)row * DD + col] = zv;
                }
                if (MODE == 0 || MODE == 1) {
                    st_s[ct] += zv;
                    st_q[ct] += zv * zv;
                }
            }
        }
    }

    if (MODE == 0 || MODE == 1) {
        const int part = blockIdx.x & (NPART - 1);
#pragma unroll
        for (int ct = 0; ct < 2; ++ct) {
            st_s[ct] += __shfl_xor(st_s[ct], 16);
            st_s[ct] += __shfl_xor(st_s[ct], 32);
            st_q[ct] += __shfl_xor(st_q[ct], 16);
            st_q[ct] += __shfl_xor(st_q[ct], 32);
            if (grp == 0) {
                const int col = wcol + ct * 16 + rl;
                unsafeAtomicAdd(&statsp[part * 256 + col], st_s[ct]);
                unsafeAtomicAdd(&statsp[part * 256 + 128 + col], st_q[ct]);
            }
        }
    }
}

// ---------------------------------------------------------------------------
// BN finalize: reduce 64 partials -> per-column scale/shift.
// ---------------------------------------------------------------------------
__global__ void bnfin_kernel(const float* __restrict__ statsp,
                             const float* __restrict__ g,
                             const float* __restrict__ beta,
                             float invN, float* ss) {
    int c = threadIdx.x;
    float s = 0.f, q = 0.f;
    for (int p = 0; p < NPART; ++p) {
        s += statsp[p * 256 + c];
        q += statsp[p * 256 + 128 + c];
    }
    float mu = s * invN;
    float var = q * invN - mu * mu;
    float sc = g[c] * rsqrtf(var + 1e-5f);
    ss[c] = sc;
    ss[128 + c] = beta[c] - mu * sc;
}

// ---------------------------------------------------------------------------

extern "C" void kernel_launch(void* const* d_in, const int* in_sizes, int n_in,
                              void* d_out, int out_size, void* d_ws, size_t ws_size,
                              hipStream_t stream) {
    const float* hT = (const float*)d_in[0];
    const float* hA = (const float*)d_in[1];
    const float* hB = (const float*)d_in[2];
    const int* src_ta = (const int*)d_in[3];
    const int* dst_ta = (const int*)d_in[4];
    const int* src_tb = (const int*)d_in[5];
    const int* dst_tb = (const int*)d_in[6];
    const int* src_at = (const int*)d_in[7];
    const int* dst_at = (const int*)d_in[8];
    const int* src_bt = (const int*)d_in[9];
    const int* dst_bt = (const int*)d_in[10];
    const float* eps_ta = (const float*)d_in[11];
    const float* eps_tb = (const float*)d_in[12];
    const float* eps_ret = (const float*)d_in[13];
    const float* ta_b1 = (const float*)d_in[15];
    const float* ta_g = (const float*)d_in[16];
    const float* ta_beta = (const float*)d_in[17];
    const float* ta_b2 = (const float*)d_in[19];
    const float* tb_b1 = (const float*)d_in[21];
    const float* tb_g = (const float*)d_in[22];
    const float* tb_beta = (const float*)d_in[23];
    const float* tb_b2 = (const float*)d_in[25];
    const float* ret_b1 = (const float*)d_in[27];
    const float* ret_g = (const float*)d_in[28];
    const float* ret_beta = (const float*)d_in[29];
    const float* ret_b2 = (const float*)d_in[31];
    const float* bp = (const float*)d_in[33];

    float* out = (float*)d_out;
    float* zT  = out;                            // [NTT*128] ret z; final hT_new (in-place)
    float* hAn = out + (size_t)NTT * DD;         // hA_new (f32 output)
    float* hBn = hAn + (size_t)NAA * DD;         // hB_new (f32 output)
    float* zA = zT;                              // ta z (rows 0..NAA)
    float* zB = zT + (size_t)NAA * DD;           // tb z (rows NAA..NTT)

    char* ws = (char*)d_ws;
    ushort_t* aggA = (ushort_t*)ws;                  // [NAA*128] bf16
    ushort_t* aggB = aggA + (size_t)NAA * DD;        // [NBB*128] bf16
    ushort_t* aggT = aggB + (size_t)NBB * DD;        // [NTT*128] bf16; becomes u
    ushort_t* Wt   = aggT + (size_t)NTT * DD;        // 7*16384 bf16
    float* statsp = (float*)(Wt + 7 * 16384);        // 3*NPART*256 f32
    float* ssb = statsp + 3 * NPART * 256;           // 3*256 f32

    // zero bf16 aggregation buffers + stats partials
    hipMemsetAsync(aggA, 0, (size_t)(NAA + NBB + NTT) * DD * 2, stream);
    hipMemsetAsync(statsp, 0, (size_t)3 * NPART * 256 * 4, stream);

    WP wp;
    wp.p[0] = (const float*)d_in[14];  // ta_W1
    wp.p[1] = (const float*)d_in[18];  // ta_W2
    wp.p[2] = (const float*)d_in[20];  // tb_W1
    wp.p[3] = (const float*)d_in[24];  // tb_W2
    wp.p[4] = (const float*)d_in[26];  // ret_W1
    wp.p[5] = (const float*)d_in[30];  // ret_W2
    wp.p[6] = (const float*)d_in[32];  // Wp
    wconv_kernel<<<(7 * 16384 + 255) / 256, 256, 0, stream>>>(wp, Wt);

    // go-path segment sums (bf16 packed atomics)
    scatter_pk_kernel<<<2048, 256, 0, stream>>>(hT, src_ta, dst_ta, aggA, NEE);
    scatter_pk_kernel<<<2048, 256, 0, stream>>>(hT, src_tb, dst_tb, aggB, NEE);

    // ta MLP
    mlp_kernel<0><<<MLP_GRID, 256, 0, stream>>>(hA, aggA, eps_ta, nullptr,
                                                Wt + 0 * 16384, ta_b1, zA,
                                                statsp + 0 * NPART * 256, NAA / 16);
    bnfin_kernel<<<1, 128, 0, stream>>>(statsp + 0 * NPART * 256, ta_g, ta_beta,
                                        1.f / NAA, ssb + 0);
    mlp_kernel<2><<<MLP_GRID, 256, 0, stream>>>(zA, nullptr, nullptr, ssb + 0,
                                                Wt + 1 * 16384, ta_b2, hAn,
                                                nullptr, NAA / 16);

    // tb MLP
    mlp_kernel<0><<<MLP_GRID, 256, 0, stream>>>(hB, aggB, eps_tb, nullptr,
                                                Wt + 2 * 16384, tb_b1, zB,
                                                statsp + 1 * NPART * 256, NBB / 16);
    bnfin_kernel<<<1, 128, 0, stream>>>(statsp + 1 * NPART * 256, tb_g, tb_beta,
                                        1.f / NBB, ssb + 256);
    mlp_kernel<2><<<MLP_GRID, 256, 0, stream>>>(zB, nullptr, nullptr, ssb + 256,
                                                Wt + 3 * 16384, tb_b2, hBn,
                                                nullptr, NBB / 16);

    // return-path segment sums into aggT (bf16)
    scatter_pk_kernel<<<2048, 256, 0, stream>>>(hAn, src_at, dst_at, aggT, NEE);
    scatter_pk_kernel<<<2048, 256, 0, stream>>>(hBn, src_bt, dst_bt, aggT, NEE);

    // projection: aggT <- bf16( (1+eps_ret)*(hT@Wp + bp) + aggT )
    mlp_kernel<3><<<MLP_GRID, 256, 0, stream>>>(hT, nullptr, eps_ret, nullptr,
                                                Wt + 6 * 16384, bp, aggT,
                                                nullptr, NTT / 16);

    // ret MLP (X = u in bf16)
    mlp_kernel<1><<<MLP_GRID, 256, 0, stream>>>(aggT, nullptr, nullptr, nullptr,
                                                Wt + 4 * 16384, ret_b1, zT,
                                                statsp + 2 * NPART * 256, NTT / 16);
    bnfin_kernel<<<1, 128, 0, stream>>>(statsp + 2 * NPART * 256, ret_g, ret_beta,
                                        1.f / NTT, ssb + 512);
    mlp_kernel<2><<<MLP_GRID, 256, 0, stream>>>(zT, nullptr, nullptr, ssb + 512,
                                                Wt + 5 * 16384, ret_b2, zT,
                                                nullptr, NTT / 16);
}

// Round 11
// 828.384 us; speedup vs baseline: 2.0437x; 1.0430x over previous
//
#include <hip/hip_runtime.h>

#define NTT 100000
#define NAA 50000
#define NBB 50000
#define NEE 500000
#define DD  128
#define NPART 64
#define MLP_GRID 2048

typedef short s16x8 __attribute__((ext_vector_type(8)));
typedef float f32x4 __attribute__((ext_vector_type(4)));
typedef unsigned short ushort_t;

__device__ inline float bf2f(unsigned short u) {
    union { unsigned int i; float f; } c;
    c.i = ((unsigned int)u) << 16;
    return c.f;
}
__device__ inline ushort_t f2bf(float f) {
    union { __bf16 b; unsigned short u; } c;
    c.b = (__bf16)f;
    return c.u;
}

// ---------------------------------------------------------------------------
// Weight convert: fp32 W[k][col] (128x128) -> bf16 W^T stored [col][k]
// ---------------------------------------------------------------------------
struct WP { const float* p[7]; };

__global__ __launch_bounds__(256) void wconv_kernel(WP wp, ushort_t* out) {
    int idx = blockIdx.x * 256 + threadIdx.x;
    if (idx >= 7 * 16384) return;
    int m = idx >> 14;
    int r = idx & 16383;
    int col = r >> 7;
    int k = r & 127;
    out[idx] = f2bf(wp.p[m][k * 128 + col]);
}

// ---------------------------------------------------------------------------
// Scatter-add segment sum into BF16 rows via packed bf16 atomics.
// At the memory-side RMW service ceiling (~19G lines/s): 4 lines/edge.
// ---------------------------------------------------------------------------
__global__ __launch_bounds__(256) void scatter_pk_kernel(const float* __restrict__ feat,
                                                         const int* __restrict__ src,
                                                         const int* __restrict__ dst,
                                                         ushort_t* agg, int nE) {
    int gtid = blockIdx.x * blockDim.x + threadIdx.x;
    int wid = gtid >> 6;
    int l = gtid & 63;
    int nw = (gridDim.x * blockDim.x) >> 6;
    for (int e = wid; e < nE; e += nw) {
        int s = src[e];
        int d = dst[e];
        const float2 v = *(const float2*)(feat + (size_t)s * DD + 2 * l);
        union { __bf16 b[2]; unsigned int u; } p;
        p.b[0] = (__bf16)v.x;
        p.b[1] = (__bf16)v.y;
        ushort_t* pa = agg + (size_t)d * DD + 2 * l;
        asm volatile("global_atomic_pk_add_bf16 %0, %1, off"
                     :: "v"(pa), "v"(p.u) : "memory");
    }
}

// ---------------------------------------------------------------------------
// Reg-B MLP GEMM. 4 waves/block, wave owns 32 cols; grid-stride 16-row tiles.
// MFMA 16x16x32 bf16; A: row=rl,k=grp*8+j; C/D: col=rl,row=grp*4+reg.
// MODE 0: X f32, A bf16 agg ; x=(1+eps)*X+A ; store z BF16 ; stats (f32)
// MODE 2: X bf16 z          ; x=relu(X*sc+sh); store f32 out (never aliases X)
// ---------------------------------------------------------------------------
template <int MODE>
__global__ __launch_bounds__(256) void mlp_kernel(const void* __restrict__ Xv,
                                                  const ushort_t* __restrict__ A,
                                                  const float* __restrict__ eps_ptr,
                                                  const float* __restrict__ ss,
                                                  const ushort_t* __restrict__ Wt,
                                                  const float* __restrict__ bias,
                                                  void* __restrict__ outv,
                                                  float* __restrict__ statsp,
                                                  int ntiles) {
    const float* X = (const float*)Xv;
    const ushort_t* Xb = (const ushort_t*)Xv;
    float* out = (float*)outv;
    ushort_t* outb = (ushort_t*)outv;

    const int tid = threadIdx.x;
    const int w = tid >> 6;
    const int l = tid & 63;
    const int rl = l & 15;
    const int grp = l >> 4;
    const int wcol = w * 32;

    s16x8 bq[2][4];
#pragma unroll
    for (int ct = 0; ct < 2; ++ct)
#pragma unroll
        for (int kc = 0; kc < 4; ++kc)
            bq[ct][kc] = *(const s16x8*)(Wt + (size_t)(wcol + ct * 16 + rl) * DD + kc * 32 + grp * 8);

    const float eps1 = (MODE == 0) ? (1.f + eps_ptr[0]) : 0.f;
    float bias_c[2];
#pragma unroll
    for (int ct = 0; ct < 2; ++ct) bias_c[ct] = bias[wcol + ct * 16 + rl];

    float st_s[2] = {0.f, 0.f}, st_q[2] = {0.f, 0.f};

    for (int t = blockIdx.x; t < ntiles; t += gridDim.x) {
        const size_t xbase = (size_t)(t * 16 + rl) * DD;
        s16x8 af[4];
#pragma unroll
        for (int kc = 0; kc < 4; ++kc) {
            const int k0 = kc * 32 + grp * 8;
            if (MODE == 0) {
                float4 v0 = *(const float4*)(X + xbase + k0);
                float4 v1 = *(const float4*)(X + xbase + k0 + 4);
                s16x8 av = *(const s16x8*)(A + xbase + k0);
                union { __bf16 h[8]; s16x8 v; } u;
                u.h[0] = (__bf16)(eps1 * v0.x + bf2f((unsigned short)av[0]));
                u.h[1] = (__bf16)(eps1 * v0.y + bf2f((unsigned short)av[1]));
                u.h[2] = (__bf16)(eps1 * v0.z + bf2f((unsigned short)av[2]));
                u.h[3] = (__bf16)(eps1 * v0.w + bf2f((unsigned short)av[3]));
                u.h[4] = (__bf16)(eps1 * v1.x + bf2f((unsigned short)av[4]));
                u.h[5] = (__bf16)(eps1 * v1.y + bf2f((unsigned short)av[5]));
                u.h[6] = (__bf16)(eps1 * v1.z + bf2f((unsigned short)av[6]));
                u.h[7] = (__bf16)(eps1 * v1.w + bf2f((unsigned short)av[7]));
                af[kc] = u.v;
            } else {
                s16x8 xv = *(const s16x8*)(Xb + xbase + k0);
                float4 c0 = *(const float4*)(ss + k0);
                float4 c1 = *(const float4*)(ss + k0 + 4);
                float4 s0 = *(const float4*)(ss + 128 + k0);
                float4 s1 = *(const float4*)(ss + 128 + k0 + 4);
                union { __bf16 h[8]; s16x8 v; } u;
                u.h[0] = (__bf16)fmaxf(bf2f((unsigned short)xv[0]) * c0.x + s0.x, 0.f);
                u.h[1] = (__bf16)fmaxf(bf2f((unsigned short)xv[1]) * c0.y + s0.y, 0.f);
                u.h[2] = (__bf16)fmaxf(bf2f((unsigned short)xv[2]) * c0.z + s0.z, 0.f);
                u.h[3] = (__bf16)fmaxf(bf2f((unsigned short)xv[3]) * c0.w + s0.w, 0.f);
                u.h[4] = (__bf16)fmaxf(bf2f((unsigned short)xv[4]) * c1.x + s1.x, 0.f);
                u.h[5] = (__bf16)fmaxf(bf2f((unsigned short)xv[5]) * c1.y + s1.y, 0.f);
                u.h[6] = (__bf16)fmaxf(bf2f((unsigned short)xv[6]) * c1.z + s1.z, 0.f);
                u.h[7] = (__bf16)fmaxf(bf2f((unsigned short)xv[7]) * c1.w + s1.w, 0.f);
                af[kc] = u.v;
            }
        }

        f32x4 acc[2] = {{0.f, 0.f, 0.f, 0.f}, {0.f, 0.f, 0.f, 0.f}};
#pragma unroll
        for (int kc = 0; kc < 4; ++kc) {
            acc[0] = __builtin_amdgcn_mfma_f32_16x16x32_bf16(af[kc], bq[0][kc], acc[0], 0, 0, 0);
            acc[1] = __builtin_amdgcn_mfma_f32_16x16x32_bf16(af[kc], bq[1][kc], acc[1], 0, 0, 0);
        }

#pragma unroll
        for (int ct = 0; ct < 2; ++ct) {
            const int col = wcol + ct * 16 + rl;
#pragma unroll
            for (int r = 0; r < 4; ++r) {
                const int row = t * 16 + grp * 4 + r;
                float zv = acc[ct][r] + bias_c[ct];
                if (MODE == 0) {
                    outb[(size_t)row * DD + col] = f2bf(zv);
                    st_s[ct] += zv;
                    st_q[ct] += zv * zv;
                } else {
                    out[(size_t)row * DD + col] = zv;
                }
            }
        }
    }

    if (MODE == 0) {
        const int part = blockIdx.x & (NPART - 1);
#pragma unroll
        for (int ct = 0; ct < 2; ++ct) {
            st_s[ct] += __shfl_xor(st_s[ct], 16);
            st_s[ct] += __shfl_xor(st_s[ct], 32);
            st_q[ct] += __shfl_xor(st_q[ct], 16);
            st_q[ct] += __shfl_xor(st_q[ct], 32);
            if (grp == 0) {
                const int col = wcol + ct * 16 + rl;
                unsafeAtomicAdd(&statsp[part * 256 + col], st_s[ct]);
                unsafeAtomicAdd(&statsp[part * 256 + 128 + col], st_q[ct]);
            }
        }
    }
}

// ---------------------------------------------------------------------------
// mode4: fused  z = ((1+eps)*(hT@Wp + bp) + aggT) @ W1 + b1  ; store z bf16.
// GEMM1 per wave (32 cols); u redistributed through LDS (16x136-pad bf16,
// double-buffered, one barrier/tile) so GEMM2 gets full-K rows; stats on z.
// Replaces the old MODE3 (u RMW to HBM) + MODE1 (u re-read) pair.
// ---------------------------------------------------------------------------
__global__ __launch_bounds__(256) void mode4_kernel(const float* __restrict__ hT,
                                                    const ushort_t* __restrict__ aggT,
                                                    const float* __restrict__ eps_ptr,
                                                    const ushort_t* __restrict__ Wpt,
                                                    const float* __restrict__ bp,
                                                    const ushort_t* __restrict__ W1t,
                                                    const float* __restrict__ b1,
                                                    ushort_t* __restrict__ zb,
                                                    float* __restrict__ statsp,
                                                    int ntiles) {
    __shared__ __align__(16) ushort_t u_lds[2][16][136];
    const int tid = threadIdx.x;
    const int w = tid >> 6;
    const int l = tid & 63;
    const int rl = l & 15;
    const int grp = l >> 4;
    const int wcol = w * 32;

    s16x8 bqp[2][4], bqr[2][4];
#pragma unroll
    for (int ct = 0; ct < 2; ++ct)
#pragma unroll
        for (int kc = 0; kc < 4; ++kc) {
            const size_t off = (size_t)(wcol + ct * 16 + rl) * DD + kc * 32 + grp * 8;
            bqp[ct][kc] = *(const s16x8*)(Wpt + off);
            bqr[ct][kc] = *(const s16x8*)(W1t + off);
        }

    const float eps1 = 1.f + eps_ptr[0];
    float bpc[2], b1c[2];
#pragma unroll
    for (int ct = 0; ct < 2; ++ct) {
        bpc[ct] = bp[wcol + ct * 16 + rl];
        b1c[ct] = b1[wcol + ct * 16 + rl];
    }

    float st_s[2] = {0.f, 0.f}, st_q[2] = {0.f, 0.f};
    int buf = 0;

    for (int t = blockIdx.x; t < ntiles; t += gridDim.x) {
        const size_t xbase = (size_t)(t * 16 + rl) * DD;
        s16x8 af[4];
#pragma unroll
        for (int kc = 0; kc < 4; ++kc) {
            const int k0 = kc * 32 + grp * 8;
            float4 v0 = *(const float4*)(hT + xbase + k0);
            float4 v1 = *(const float4*)(hT + xbase + k0 + 4);
            union { __bf16 h[8]; s16x8 v; } u;
            u.h[0] = (__bf16)v0.x; u.h[1] = (__bf16)v0.y;
            u.h[2] = (__bf16)v0.z; u.h[3] = (__bf16)v0.w;
            u.h[4] = (__bf16)v1.x; u.h[5] = (__bf16)v1.y;
            u.h[6] = (__bf16)v1.z; u.h[7] = (__bf16)v1.w;
            af[kc] = u.v;
        }

        f32x4 acc1[2] = {{0.f, 0.f, 0.f, 0.f}, {0.f, 0.f, 0.f, 0.f}};
#pragma unroll
        for (int kc = 0; kc < 4; ++kc) {
            acc1[0] = __builtin_amdgcn_mfma_f32_16x16x32_bf16(af[kc], bqp[0][kc], acc1[0], 0, 0, 0);
            acc1[1] = __builtin_amdgcn_mfma_f32_16x16x32_bf16(af[kc], bqp[1][kc], acc1[1], 0, 0, 0);
        }

        // u = (1+eps)*(proj + bp) + aggT  ->  LDS (bf16)
#pragma unroll
        for (int ct = 0; ct < 2; ++ct) {
            const int col = wcol + ct * 16 + rl;
#pragma unroll
            for (int r = 0; r < 4; ++r) {
                const int lrow = grp * 4 + r;
                const size_t row = (size_t)(t * 16 + lrow);
                float uv = eps1 * (acc1[ct][r] + bpc[ct]) + bf2f(aggT[row * DD + col]);
                u_lds[buf][lrow][col] = f2bf(uv);
            }
        }
        __syncthreads();

        s16x8 af2[4];
#pragma unroll
        for (int kc = 0; kc < 4; ++kc)
            af2[kc] = *(const s16x8*)&u_lds[buf][rl][kc * 32 + grp * 8];

        f32x4 acc2[2] = {{0.f, 0.f, 0.f, 0.f}, {0.f, 0.f, 0.f, 0.f}};
#pragma unroll
        for (int kc = 0; kc < 4; ++kc) {
            acc2[0] = __builtin_amdgcn_mfma_f32_16x16x32_bf16(af2[kc], bqr[0][kc], acc2[0], 0, 0, 0);
            acc2[1] = __builtin_amdgcn_mfma_f32_16x16x32_bf16(af2[kc], bqr[1][kc], acc2[1], 0, 0, 0);
        }

#pragma unroll
        for (int ct = 0; ct < 2; ++ct) {
            const int col = wcol + ct * 16 + rl;
#pragma unroll
            for (int r = 0; r < 4; ++r) {
                const int row = t * 16 + grp * 4 + r;
                float zv = acc2[ct][r] + b1c[ct];
                zb[(size_t)row * DD + col] = f2bf(zv);
                st_s[ct] += zv;
                st_q[ct] += zv * zv;
            }
        }
        buf ^= 1;
    }

    const int part = blockIdx.x & (NPART - 1);
#pragma unroll
    for (int ct = 0; ct < 2; ++ct) {
        st_s[ct] += __shfl_xor(st_s[ct], 16);
        st_s[ct] += __shfl_xor(st_s[ct], 32);
        st_q[ct] += __shfl_xor(st_q[ct], 16);
        st_q[ct] += __shfl_xor(st_q[ct], 32);
        if (grp == 0) {
            const int col = wcol + ct * 16 + rl;
            unsafeAtomicAdd(&statsp[part * 256 + col], st_s[ct]);
            unsafeAtomicAdd(&statsp[part * 256 + 128 + col], st_q[ct]);
        }
    }
}

// ---------------------------------------------------------------------------
// BN finalize: reduce 64 partials -> per-column scale/shift.
// ---------------------------------------------------------------------------
__global__ void bnfin_kernel(const float* __restrict__ statsp,
                             const float* __restrict__ g,
                             const float* __restrict__ beta,
                             float invN, float* ss) {
    int c = threadIdx.x;
    float s = 0.f, q = 0.f;
    for (int p = 0; p < NPART; ++p) {
        s += statsp[p * 256 + c];
        q += statsp[p * 256 + 128 + c];
    }
    float mu = s * invN;
    float var = q * invN - mu * mu;
    float sc = g[c] * rsqrtf(var + 1e-5f);
    ss[c] = sc;
    ss[128 + c] = beta[c] - mu * sc;
}

// ---------------------------------------------------------------------------

extern "C" void kernel_launch(void* const* d_in, const int* in_sizes, int n_in,
                              void* d_out, int out_size, void* d_ws, size_t ws_size,
                              hipStream_t stream) {
    const float* hT = (const float*)d_in[0];
    const float* hA = (const float*)d_in[1];
    const float* hB = (const float*)d_in[2];
    const int* src_ta = (const int*)d_in[3];
    const int* dst_ta = (const int*)d_in[4];
    const int* src_tb = (const int*)d_in[5];
    const int* dst_tb = (const int*)d_in[6];
    const int* src_at = (const int*)d_in[7];
    const int* dst_at = (const int*)d_in[8];
    const int* src_bt = (const int*)d_in[9];
    const int* dst_bt = (const int*)d_in[10];
    const float* eps_ta = (const float*)d_in[11];
    const float* eps_tb = (const float*)d_in[12];
    const float* eps_ret = (const float*)d_in[13];
    const float* ta_b1 = (const float*)d_in[15];
    const float* ta_g = (const float*)d_in[16];
    const float* ta_beta = (const float*)d_in[17];
    const float* ta_b2 = (const float*)d_in[19];
    const float* tb_b1 = (const float*)d_in[21];
    const float* tb_g = (const float*)d_in[22];
    const float* tb_beta = (const float*)d_in[23];
    const float* tb_b2 = (const float*)d_in[25];
    const float* ret_b1 = (const float*)d_in[27];
    const float* ret_g = (const float*)d_in[28];
    const float* ret_beta = (const float*)d_in[29];
    const float* ret_b2 = (const float*)d_in[31];
    const float* bp = (const float*)d_in[33];

    float* out = (float*)d_out;
    float* hTn = out;                            // final hT_new
    float* hAn = out + (size_t)NTT * DD;         // hA_new
    float* hBn = hAn + (size_t)NAA * DD;         // hB_new

    // ws: two 25.6MB regions with lifetime overlays + weights/stats.
    // R0: aggA,aggB (until MODE0s) -> zT (mode4 .. final MODE2)
    // R1: zA,zB (until MODE2s)     -> aggT (memset after tb-MODE2 .. mode4)
    char* ws = (char*)d_ws;
    ushort_t* R0 = (ushort_t*)ws;
    ushort_t* aggA = R0;
    ushort_t* aggB = R0 + (size_t)NAA * DD;
    ushort_t* zT   = R0;
    ushort_t* R1 = R0 + (size_t)NTT * DD;
    ushort_t* zA = R1;
    ushort_t* zB = R1 + (size_t)NAA * DD;
    ushort_t* aggT = R1;
    ushort_t* Wt = R1 + (size_t)NTT * DD;
    float* statsp = (float*)(Wt + 7 * 16384);
    float* ssb = statsp + 3 * NPART * 256;

    hipMemsetAsync(aggA, 0, (size_t)NTT * DD * 2, stream);   // aggA+aggB
    hipMemsetAsync(statsp, 0, (size_t)3 * NPART * 256 * 4, stream);

    WP wp;
    wp.p[0] = (const float*)d_in[14];  // ta_W1
    wp.p[1] = (const float*)d_in[18];  // ta_W2
    wp.p[2] = (const float*)d_in[20];  // tb_W1
    wp.p[3] = (const float*)d_in[24];  // tb_W2
    wp.p[4] = (const float*)d_in[26];  // ret_W1
    wp.p[5] = (const float*)d_in[30];  // ret_W2
    wp.p[6] = (const float*)d_in[32];  // Wp
    wconv_kernel<<<(7 * 16384 + 255) / 256, 256, 0, stream>>>(wp, Wt);

    // go-path segment sums
    scatter_pk_kernel<<<2048, 256, 0, stream>>>(hT, src_ta, dst_ta, aggA, NEE);
    scatter_pk_kernel<<<2048, 256, 0, stream>>>(hT, src_tb, dst_tb, aggB, NEE);

    // ta/tb first GEMM + BN stats
    mlp_kernel<0><<<MLP_GRID, 256, 0, stream>>>(hA, aggA, eps_ta, nullptr,
                                                Wt + 0 * 16384, ta_b1, zA,
                                                statsp + 0 * NPART * 256, NAA / 16);
    mlp_kernel<0><<<MLP_GRID, 256, 0, stream>>>(hB, aggB, eps_tb, nullptr,
                                                Wt + 2 * 16384, tb_b1, zB,
                                                statsp + 1 * NPART * 256, NBB / 16);
    bnfin_kernel<<<1, 128, 0, stream>>>(statsp + 0 * NPART * 256, ta_g, ta_beta,
                                        1.f / NAA, ssb + 0);
    bnfin_kernel<<<1, 128, 0, stream>>>(statsp + 1 * NPART * 256, tb_g, tb_beta,
                                        1.f / NBB, ssb + 256);

    // ta/tb second GEMM -> hA_new, hB_new (f32 outputs)
    mlp_kernel<2><<<MLP_GRID, 256, 0, stream>>>(zA, nullptr, nullptr, ssb + 0,
                                                Wt + 1 * 16384, ta_b2, hAn,
                                                nullptr, NAA / 16);
    mlp_kernel<2><<<MLP_GRID, 256, 0, stream>>>(zB, nullptr, nullptr, ssb + 256,
                                                Wt + 3 * 16384, tb_b2, hBn,
                                                nullptr, NBB / 16);

    // aggT overlays zA/zB — zero it only after they are consumed
    hipMemsetAsync(aggT, 0, (size_t)NTT * DD * 2, stream);

    // return-path segment sums
    scatter_pk_kernel<<<2048, 256, 0, stream>>>(hAn, src_at, dst_at, aggT, NEE);
    scatter_pk_kernel<<<2048, 256, 0, stream>>>(hBn, src_bt, dst_bt, aggT, NEE);

    // fused projection + add + GEMM1(ret) + stats  (zT overlays dead aggA/aggB)
    mode4_kernel<<<MLP_GRID, 256, 0, stream>>>(hT, aggT, eps_ret,
                                               Wt + 6 * 16384, bp,
                                               Wt + 4 * 16384, ret_b1,
                                               zT, statsp + 2 * NPART * 256, NTT / 16);
    bnfin_kernel<<<1, 128, 0, stream>>>(statsp + 2 * NPART * 256, ret_g, ret_beta,
                                        1.f / NTT, ssb + 512);

    // final GEMM -> hT_new
    mlp_kernel<2><<<MLP_GRID, 256, 0, stream>>>(zT, nullptr, nullptr, ssb + 512,
                                                Wt + 5 * 16384, ret_b2, hTn,
                                                nullptr, NTT / 16);
}